// Round 19
// baseline (306.440 us; speedup 1.0000x reference)
//
#include <hip/hip_runtime.h>

#define CI 64
#define CO 128
#define HH 64
#define WW 64
#define OH 62
#define OW 62
#define XTW 66          // padded row width in LDS: 64 real cols + 2 zero cols
#define RB (XTW * 64)   // ushorts per staged input row = 4224 (8448 B)
#define ROWS_OUT 8      // output rows per block (two 4-row tiles)
#define NSLOT 8         // LDS row-ring slots (rows 8,9 reuse slots 0,1)
#define NBLK_X 8        // ceil(62/8); last block masks oh>=62

typedef __attribute__((ext_vector_type(8))) short short8x;
typedef __attribute__((ext_vector_type(16))) float f32x16;

// Weight scratch in a module device-global (not d_ws); wprep rewrites it
// every launch (idempotent, graph-capture safe).  ~3 us, L2-resident.
__device__ __attribute__((aligned(16))) ushort g_wt[9 * CO * CI];   // [tap][co][ci] bf16

__device__ __forceinline__ ushort bf16rne(float f) {
    unsigned u = __builtin_bit_cast(unsigned, f);
    u += 0x7fffu + ((u >> 16) & 1u);
    return (ushort)(u >> 16);
}

__global__ __launch_bounds__(256)
void wprep(const float* __restrict__ w) {
    const int idx = blockIdx.x * 256 + threadIdx.x;   // 73728 total
    const int kk = idx >> 13;
    const int rem = idx & 8191;
    const int co = rem >> 6, ci = rem & 63;
    g_wt[idx] = bf16rne(w[(co * 64 + ci) * 9 + kk]);
}

// 2-tile pipelined conv (r16 base): 256 thr, 4 waves = co-half x rw, 2 rows
// per wave per tile.  Block owns 8 output rows as two 4-row tiles over an
// 8-slot LDS row-ring (rows 8,9 -> slots 0,1 after tile1 retires them).
// KEY CHANGE vs r16: tile1's 128 stores are issued AFTER barrier C and
// BEFORE tile2's K-loop -> they L2-drain under ~12us of MFMA instead of
// serializing at block end (r16's serial-phase wall: waves feed HBM only
// ~30% of the time).  Tile2's tap-0 weight loads are issued BEFORE the
// stores so their counted vmcnt waits don't force a store drain (vmcnt
// retires in issue order).  Grid 8x64=512 blocks = 2/CU = exactly ONE
// dispatch round, zero tail.  Staging redundancy 1.5x -> 1.25x.
__global__ __launch_bounds__(256, 2)
void conv_fused(const float* __restrict__ x, const float* __restrict__ bias,
                float* __restrict__ out) {
    __shared__ ushort Xl[NSLOT * RB];   // 67,584 B -> 2 blocks/CU
    __shared__ float  sB[CO];

    const int tid = threadIdx.x;
    const int wv = tid >> 6, L = tid & 63, l31 = L & 31, q = L >> 5;
    const int h = wv >> 1;           // co half: co base = h*64
    const int rw = wv & 1;           // wave's first row-in-tile; second = rw+2
    const int b = blockIdx.y, oh0 = blockIdx.x * ROWS_OUT;

    if (tid < CO) sB[tid] = bias[tid];

    // ---- tile1 tap-0 A-fragment loads (verified layout: m=l31, k=q*8+j) ----
    const ushort* wbase = g_wt + (h * 64 + l31) * 64 + q * 8;
    short8x wbuf[2][8];   // [dbuf][m*4+s]
    #pragma unroll
    for (int m = 0; m < 2; ++m)
        #pragma unroll
        for (int ss = 0; ss < 4; ++ss)
            wbuf[0][m * 4 + ss] = *(const short8x*)(wbase + m * 2048 + ss * 16);

    // ---- zero-pad pixels 64,65 of all 8 slots (128 x uint4) ----
    if (tid < 128) {
        const int s8 = tid >> 4, c = tid & 15;
        const int px = 64 + (c >> 3), slot = c & 7;
        const uint4 z{0, 0, 0, 0};
        *reinterpret_cast<uint4*>(&Xl[(s8 * XTW + px) * 64 + slot * 8]) = z;
    }

    // ---- phase 1: stage rows 0..7 into slots 0..7 (coalesced + in-reg T) ----
    const int w = L;
    const size_t cibase = (size_t)(b * 64 + wv * 16) * (HH * WW);
    #pragma unroll
    for (int r8 = 0; r8 < 8; ++r8) {
        int ir = oh0 + r8;
        if (ir > 63) ir = 63;                 // last strip clamp (dummy)
        const float* src = x + cibase + (size_t)ir * WW + w;
        union { ushort u[8]; uint4 v; } p0, p1;
        #pragma unroll
        for (int k = 0; k < 8; ++k)
            p0.u[k] = bf16rne(src[(size_t)k * (HH * WW)]);
        #pragma unroll
        for (int k = 0; k < 8; ++k)
            p1.u[k] = bf16rne(src[(size_t)(8 + k) * (HH * WW)]);
        const int pl = r8 * XTW + w, key = pl & 7;
        ushort* dst = &Xl[pl * 64];
        *reinterpret_cast<uint4*>(dst + (((2 * wv)     ^ key) * 8)) = p0.v;
        *reinterpret_cast<uint4*>(dst + (((2 * wv + 1) ^ key) * 8)) = p1.v;
    }

    f32x16 acc[2][2][2];   // [row2][mt][nt] -- 128 AGPRs (reused per tile)
    #pragma unroll
    for (int r2 = 0; r2 < 2; ++r2)
        #pragma unroll
        for (int i = 0; i < 2; ++i)
            #pragma unroll
            for (int jj = 0; jj < 2; ++jj)
                #pragma unroll
                for (int r = 0; r < 16; ++r) acc[r2][i][jj][r] = 0.f;

    __syncthreads();   // barrier A: slots 0..7 + pads visible

    // ---- issue rows 8,9 loads NOW (latency hides under tile1's K-loop) ----
    float v89[2][16];
    #pragma unroll
    for (int r2 = 0; r2 < 2; ++r2) {
        int ir = oh0 + 8 + r2;
        if (ir > 63) ir = 63;                 // clamp (dummy; outputs masked)
        const float* src = x + cibase + (size_t)ir * WW + w;
        #pragma unroll
        for (int k = 0; k < 16; ++k)
            v89[r2][k] = src[(size_t)k * (HH * WW)];
    }

    // ================= tile 1: output rows oh0+rw, oh0+rw+2 =================
    #pragma unroll
    for (int kk = 0; kk < 9; ++kk) {
        const short8x* wf = wbuf[kk & 1];
        if (kk < 8) {   // prefetch next tap's A
            const ushort* nb = wbase + (kk + 1) * (CO * CI);
            #pragma unroll
            for (int m = 0; m < 2; ++m)
                #pragma unroll
                for (int ss = 0; ss < 4; ++ss)
                    wbuf[(kk + 1) & 1][m * 4 + ss] = *(const short8x*)(nb + m * 2048 + ss * 16);
        }
        const int kr = kk / 3, kc = kk - kr * 3;
        const int pBa = (rw + kr) * XTW + kc + l31;       // slot rw+kr (<=3)
        const int pBb = (rw + 2 + kr) * XTW + kc + l31;   // slot rw+2+kr (<=5)
        const ushort* bPa = Xl + pBa * 64;
        const ushort* bPb = Xl + pBb * 64;
        const int f0a = pBa & 7, f0b = pBb & 7;
        #pragma unroll
        for (int ss = 0; ss < 4; ++ss) {
            const int oba = (((ss * 2 + q) ^ f0a) * 8);
            const int obb = (((ss * 2 + q) ^ f0b) * 8);
            short8x a0 = *(const short8x*)(bPa + oba);
            short8x a1 = *(const short8x*)(bPa + 32 * 64 + oba);
            short8x c0 = *(const short8x*)(bPb + obb);
            short8x c1 = *(const short8x*)(bPb + 32 * 64 + obb);
            acc[0][0][0] = __builtin_amdgcn_mfma_f32_32x32x16_bf16(wf[ss],     a0, acc[0][0][0], 0, 0, 0);
            acc[0][0][1] = __builtin_amdgcn_mfma_f32_32x32x16_bf16(wf[ss],     a1, acc[0][0][1], 0, 0, 0);
            acc[0][1][0] = __builtin_amdgcn_mfma_f32_32x32x16_bf16(wf[4 + ss], a0, acc[0][1][0], 0, 0, 0);
            acc[0][1][1] = __builtin_amdgcn_mfma_f32_32x32x16_bf16(wf[4 + ss], a1, acc[0][1][1], 0, 0, 0);
            acc[1][0][0] = __builtin_amdgcn_mfma_f32_32x32x16_bf16(wf[ss],     c0, acc[1][0][0], 0, 0, 0);
            acc[1][0][1] = __builtin_amdgcn_mfma_f32_32x32x16_bf16(wf[ss],     c1, acc[1][0][1], 0, 0, 0);
            acc[1][1][0] = __builtin_amdgcn_mfma_f32_32x32x16_bf16(wf[4 + ss], c0, acc[1][1][0], 0, 0, 0);
            acc[1][1][1] = __builtin_amdgcn_mfma_f32_32x32x16_bf16(wf[4 + ss], c1, acc[1][1][1], 0, 0, 0);
        }
    }

    __syncthreads();   // barrier B: all waves done reading slots 0,1

    // ---- cvt + ds_write rows 8,9 into slots 0,1 ----
    #pragma unroll
    for (int r2 = 0; r2 < 2; ++r2) {
        union { ushort u[8]; uint4 v; } p0, p1;
        #pragma unroll
        for (int k = 0; k < 8; ++k) p0.u[k] = bf16rne(v89[r2][k]);
        #pragma unroll
        for (int k = 0; k < 8; ++k) p1.u[k] = bf16rne(v89[r2][8 + k]);
        const int pl = r2 * XTW + w, key = pl & 7;        // slot r2 (0,1)
        ushort* dst = &Xl[pl * 64];
        *reinterpret_cast<uint4*>(dst + (((2 * wv)     ^ key) * 8)) = p0.v;
        *reinterpret_cast<uint4*>(dst + (((2 * wv + 1) ^ key) * 8)) = p1.v;
    }

    __syncthreads();   // barrier C: slots 0,1 now hold rows 8,9

    // ---- tile2 tap-0 weights FIRST (so their waits precede the stores) ----
    #pragma unroll
    for (int m = 0; m < 2; ++m)
        #pragma unroll
        for (int ss = 0; ss < 4; ++ss)
            wbuf[0][m * 4 + ss] = *(const short8x*)(wbase + m * 2048 + ss * 16);

    // ---- tile1 epilogue NOW: stores drain under tile2's K-loop ----
    #pragma unroll
    for (int r2 = 0; r2 < 2; ++r2) {
        const int oh = oh0 + rw + 2 * r2;                 // <= 59, in-bounds
        #pragma unroll
        for (int mt = 0; mt < 2; ++mt)
            #pragma unroll
            for (int nt = 0; nt < 2; ++nt) {
                const int col = nt * 32 + l31;
                if (col < OW) {
                    #pragma unroll
                    for (int reg = 0; reg < 16; ++reg) {
                        const int co = h * 64 + mt * 32 + 4 * q + (reg & 3) + 8 * (reg >> 2);
                        out[(((size_t)b * CO + co) * OH + oh) * OW + col] = acc[r2][mt][nt][reg] + sB[co];
                    }
                }
            }
    }

    // ---- reset acc for tile 2 ----
    #pragma unroll
    for (int r2 = 0; r2 < 2; ++r2)
        #pragma unroll
        for (int i = 0; i < 2; ++i)
            #pragma unroll
            for (int jj = 0; jj < 2; ++jj)
                #pragma unroll
                for (int r = 0; r < 16; ++r) acc[r2][i][jj][r] = 0.f;

    // ================= tile 2: output rows oh0+4+rw, oh0+6+rw ===============
    #pragma unroll
    for (int kk = 0; kk < 9; ++kk) {
        const short8x* wf = wbuf[kk & 1];
        if (kk < 8) {   // prefetch next tap's A
            const ushort* nb = wbase + (kk + 1) * (CO * CI);
            #pragma unroll
            for (int m = 0; m < 2; ++m)
                #pragma unroll
                for (int ss = 0; ss < 4; ++ss)
                    wbuf[(kk + 1) & 1][m * 4 + ss] = *(const short8x*)(nb + m * 2048 + ss * 16);
        }
        const int kr = kk / 3, kc = kk - kr * 3;
        const int sa = (4 + rw + kr) & 7;                 // slot of row 4+rw+kr
        const int sb2 = (6 + rw + kr) & 7;                // slot of row 6+rw+kr
        const int pBa = sa * XTW + kc + l31;
        const int pBb = sb2 * XTW + kc + l31;
        const ushort* bPa = Xl + pBa * 64;
        const ushort* bPb = Xl + pBb * 64;
        const int f0a = pBa & 7, f0b = pBb & 7;
        #pragma unroll
        for (int ss = 0; ss < 4; ++ss) {
            const int oba = (((ss * 2 + q) ^ f0a) * 8);
            const int obb = (((ss * 2 + q) ^ f0b) * 8);
            short8x a0 = *(const short8x*)(bPa + oba);
            short8x a1 = *(const short8x*)(bPa + 32 * 64 + oba);
            short8x c0 = *(const short8x*)(bPb + obb);
            short8x c1 = *(const short8x*)(bPb + 32 * 64 + obb);
            acc[0][0][0] = __builtin_amdgcn_mfma_f32_32x32x16_bf16(wf[ss],     a0, acc[0][0][0], 0, 0, 0);
            acc[0][0][1] = __builtin_amdgcn_mfma_f32_32x32x16_bf16(wf[ss],     a1, acc[0][0][1], 0, 0, 0);
            acc[0][1][0] = __builtin_amdgcn_mfma_f32_32x32x16_bf16(wf[4 + ss], a0, acc[0][1][0], 0, 0, 0);
            acc[0][1][1] = __builtin_amdgcn_mfma_f32_32x32x16_bf16(wf[4 + ss], a1, acc[0][1][1], 0, 0, 0);
            acc[1][0][0] = __builtin_amdgcn_mfma_f32_32x32x16_bf16(wf[ss],     c0, acc[1][0][0], 0, 0, 0);
            acc[1][0][1] = __builtin_amdgcn_mfma_f32_32x32x16_bf16(wf[ss],     c1, acc[1][0][1], 0, 0, 0);
            acc[1][1][0] = __builtin_amdgcn_mfma_f32_32x32x16_bf16(wf[4 + ss], c0, acc[1][1][0], 0, 0, 0);
            acc[1][1][1] = __builtin_amdgcn_mfma_f32_32x32x16_bf16(wf[4 + ss], c1, acc[1][1][1], 0, 0, 0);
        }
    }

    // ---- tile2 terminal epilogue (oh >= 62 masked on last strip) ----
    #pragma unroll
    for (int r2 = 0; r2 < 2; ++r2) {
        const int oh = oh0 + 4 + rw + 2 * r2;
        if (oh < OH) {
            #pragma unroll
            for (int mt = 0; mt < 2; ++mt)
                #pragma unroll
                for (int nt = 0; nt < 2; ++nt) {
                    const int col = nt * 32 + l31;
                    if (col < OW) {
                        #pragma unroll
                        for (int reg = 0; reg < 16; ++reg) {
                            const int co = h * 64 + mt * 32 + 4 * q + (reg & 3) + 8 * (reg >> 2);
                            out[(((size_t)b * CO + co) * OH + oh) * OW + col] = acc[r2][mt][nt][reg] + sB[co];
                        }
                    }
                }
        }
    }
}

extern "C" void kernel_launch(void* const* d_in, const int* in_sizes, int n_in,
                              void* d_out, int out_size, void* d_ws, size_t ws_size,
                              hipStream_t stream) {
    const float* x    = (const float*)d_in[0];
    const float* wgt  = (const float*)d_in[1];
    const float* bias = (const float*)d_in[2];
    float* out = (float*)d_out;

    wprep<<<dim3(288), 256, 0, stream>>>(wgt);
    conv_fused<<<dim3(NBLK_X, 64), 256, 0, stream>>>(x, bias, out);
}